// Round 2
// baseline (3863.267 us; speedup 1.0000x reference)
//
#include <hip/hip_runtime.h>
#include <hip/hip_bf16.h>

#define TILE 64
#define BK 16

typedef unsigned int uint32;

__device__ __forceinline__ float bf_lo(uint32 q) {
    union { uint32 u; float f; } v; v.u = q << 16; return v.f;
}
__device__ __forceinline__ float bf_hi(uint32 q) {
    union { uint32 u; float f; } v; v.u = q & 0xffff0000u; return v.f;
}

// ============ K1: XL/XR = relu(x@W_node+b_node) @ W + b, bf16 out ============
__global__ __launch_bounds__(256) void node_gemm(
    const float* __restrict__ x,    // [M,7]
    const float* __restrict__ Wn,   // [7,512]
    const float* __restrict__ bn,   // [512]
    const float* __restrict__ W,    // [512,2048]
    const float* __restrict__ b,    // [2048]
    __hip_bfloat16* __restrict__ O, // [M,2048]
    int M)
{
    __shared__ float As[BK][TILE + 4];
    __shared__ float Ws[BK][TILE + 4];
    __shared__ float xs[TILE][8];
    int row0 = blockIdx.x * TILE, col0 = blockIdx.y * TILE;
    int t = threadIdx.x, tx = t & 15, ty = t >> 4;

    if (t < TILE * 2) {           // stage x rows: 128 threads, 2 per row
        int r = t >> 1, half = t & 1;
        int gr = row0 + r;
        for (int f = half * 4; f < half * 4 + 4; ++f)
            if (f < 7) xs[r][f] = (gr < M) ? x[gr * 7 + f] : 0.f;
    }
    __syncthreads();

    float acc[4][4] = {};
    for (int k0 = 0; k0 < 512; k0 += BK) {
        #pragma unroll
        for (int i = 0; i < 4; ++i) {
            int idx = i * 256 + t, ar = idx >> 4, ac = idx & 15;
            int gc = k0 + ac;
            float v = bn[gc];
            #pragma unroll
            for (int f = 0; f < 7; ++f) v += xs[ar][f] * Wn[f * 512 + gc];
            As[ac][ar] = fmaxf(v, 0.f);
        }
        #pragma unroll
        for (int i = 0; i < 4; ++i) {
            int idx = i * 256 + t, wr = idx >> 6, wc = idx & 63;
            Ws[wr][wc] = W[(size_t)(k0 + wr) * 2048 + col0 + wc];
        }
        __syncthreads();
        #pragma unroll
        for (int k = 0; k < BK; ++k) {
            float4 a4 = *(const float4*)&As[k][ty * 4];
            float4 b4 = *(const float4*)&Ws[k][tx * 4];
            float av[4] = {a4.x, a4.y, a4.z, a4.w};
            float bv[4] = {b4.x, b4.y, b4.z, b4.w};
            #pragma unroll
            for (int i = 0; i < 4; ++i)
                #pragma unroll
                for (int j = 0; j < 4; ++j)
                    acc[i][j] += av[i] * bv[j];
        }
        __syncthreads();
    }
    #pragma unroll
    for (int i = 0; i < 4; ++i) {
        int gr = row0 + ty * 4 + i;
        if (gr >= M) continue;
        #pragma unroll
        for (int j = 0; j < 4; ++j) {
            int gc = col0 + tx * 4 + j;
            O[(size_t)gr * 2048 + gc] = __float2bfloat16(acc[i][j] + b[gc]);
        }
    }
}

// ===== K2: EE GEMM (edge encoder fused in A) + logits epilogue =====
__global__ __launch_bounds__(256) void edge_gemm_logits(
    const float* __restrict__ eat,  // [E,2]
    const float* __restrict__ We,   // [2,512]
    const float* __restrict__ be,   // [512]
    const float* __restrict__ Wle,  // [512,2048]
    const __hip_bfloat16* __restrict__ XL,
    const __hip_bfloat16* __restrict__ XR,
    const int* __restrict__ ei,     // [2,E]
    const float* __restrict__ att,  // [4,512]
    float* __restrict__ logits,     // [E,4] (pre-zeroed)
    int E)
{
    __shared__ float As[BK][TILE + 4];
    __shared__ float Ws[BK][TILE + 4];
    __shared__ float es[TILE][2];
    __shared__ int srcs[TILE], dsts[TILE];
    int row0 = blockIdx.x * TILE, col0 = blockIdx.y * TILE;
    int t = threadIdx.x, tx = t & 15, ty = t >> 4;

    if (t < TILE) {
        int ge = row0 + t;
        bool ok = ge < E;
        es[t][0] = ok ? eat[ge * 2] : 0.f;
        es[t][1] = ok ? eat[ge * 2 + 1] : 0.f;
        srcs[t] = ok ? ei[ge] : 0;
        dsts[t] = ok ? ei[E + ge] : 0;
    }
    __syncthreads();

    float acc[4][4] = {};
    for (int k0 = 0; k0 < 512; k0 += BK) {
        #pragma unroll
        for (int i = 0; i < 4; ++i) {
            int idx = i * 256 + t, ar = idx >> 4, ac = idx & 15;
            int gc = k0 + ac;
            float v = es[ar][0] * We[gc] + es[ar][1] * We[512 + gc] + be[gc];
            As[ac][ar] = fmaxf(v, 0.f);
        }
        #pragma unroll
        for (int i = 0; i < 4; ++i) {
            int idx = i * 256 + t, wr = idx >> 6, wc = idx & 63;
            Ws[wr][wc] = Wle[(size_t)(k0 + wr) * 2048 + col0 + wc];
        }
        __syncthreads();
        #pragma unroll
        for (int k = 0; k < BK; ++k) {
            float4 a4 = *(const float4*)&As[k][ty * 4];
            float4 b4 = *(const float4*)&Ws[k][tx * 4];
            float av[4] = {a4.x, a4.y, a4.z, a4.w};
            float bv[4] = {b4.x, b4.y, b4.z, b4.w};
            #pragma unroll
            for (int i = 0; i < 4; ++i)
                #pragma unroll
                for (int j = 0; j < 4; ++j)
                    acc[i][j] += av[i] * bv[j];
        }
        __syncthreads();
    }
    // epilogue: logits[e,h] += sum_cols att[h,c]*leaky(ee + xl[src] + xr[dst])
    int h = col0 >> 9;
    const float* atth = att + h * 512;
    float part[4] = {0.f, 0.f, 0.f, 0.f};
    #pragma unroll
    for (int i = 0; i < 4; ++i) {
        int er = ty * 4 + i;
        int ge = row0 + er;
        if (ge >= E) continue;
        int s = srcs[er], d = dsts[er];
        #pragma unroll
        for (int j = 0; j < 4; ++j) {
            int gc = col0 + tx * 4 + j;
            float m = acc[i][j]
                    + __bfloat162float(XL[(size_t)s * 2048 + gc])
                    + __bfloat162float(XR[(size_t)d * 2048 + gc]);
            float sv = (m > 0.f) ? m : 0.2f * m;
            part[i] += atth[gc & 511] * sv;
        }
    }
    #pragma unroll
    for (int off = 1; off < 16; off <<= 1)
        #pragma unroll
        for (int i = 0; i < 4; ++i) part[i] += __shfl_xor(part[i], off);
    if (tx == 0) {
        #pragma unroll
        for (int i = 0; i < 4; ++i) {
            int ge = row0 + ty * 4 + i;
            if (ge < E) atomicAdd(&logits[ge * 4 + h], part[i]);
        }
    }
}

// ============ K3: Y[n,h,:] = XL[n, h*512:(h+1)*512] @ W_d1[h*512:, :] ============
__global__ __launch_bounds__(256) void y_gemm(
    const __hip_bfloat16* __restrict__ XL, // [M,2048]
    const float* __restrict__ Wd1,         // [2048,512]
    __hip_bfloat16* __restrict__ Y,        // [M,4,512]
    int M)
{
    int h = blockIdx.z;
    __shared__ float As[BK][TILE + 4];
    __shared__ float Ws[BK][TILE + 4];
    int row0 = blockIdx.x * TILE, col0 = blockIdx.y * TILE;
    int t = threadIdx.x, tx = t & 15, ty = t >> 4;
    float acc[4][4] = {};
    for (int k0 = 0; k0 < 512; k0 += BK) {
        #pragma unroll
        for (int i = 0; i < 4; ++i) {
            int idx = i * 256 + t, ar = idx >> 4, ac = idx & 15;
            int gr = row0 + ar;
            As[ac][ar] = (gr < M)
                ? __bfloat162float(XL[(size_t)gr * 2048 + h * 512 + k0 + ac]) : 0.f;
        }
        #pragma unroll
        for (int i = 0; i < 4; ++i) {
            int idx = i * 256 + t, wr = idx >> 6, wc = idx & 63;
            Ws[wr][wc] = Wd1[(size_t)(h * 512 + k0 + wr) * 512 + col0 + wc];
        }
        __syncthreads();
        #pragma unroll
        for (int k = 0; k < BK; ++k) {
            float4 a4 = *(const float4*)&As[k][ty * 4];
            float4 b4 = *(const float4*)&Ws[k][tx * 4];
            float av[4] = {a4.x, a4.y, a4.z, a4.w};
            float bv[4] = {b4.x, b4.y, b4.z, b4.w};
            #pragma unroll
            for (int i = 0; i < 4; ++i)
                #pragma unroll
                for (int j = 0; j < 4; ++j)
                    acc[i][j] += av[i] * bv[j];
        }
        __syncthreads();
    }
    #pragma unroll
    for (int i = 0; i < 4; ++i) {
        int gr = row0 + ty * 4 + i;
        if (gr >= M) continue;
        #pragma unroll
        for (int j = 0; j < 4; ++j) {
            int gc = col0 + tx * 4 + j;
            Y[((size_t)gr * 4 + h) * 512 + gc] = __float2bfloat16(acc[i][j]);
        }
    }
}

// ============ K4: exp + denominator scatter ============
__global__ __launch_bounds__(256) void softmax_den(
    const float* __restrict__ logits, const int* __restrict__ ei,
    float* __restrict__ exb, float* __restrict__ den, int E)
{
    int idx = blockIdx.x * 256 + threadIdx.x;
    if (idx >= E * 4) return;
    int e = idx >> 2, h = idx & 3;
    // softmax is shift-invariant; logits here are O(0.1) so no running max needed
    float ex = expf(logits[idx]);
    exb[idx] = ex;
    atomicAdd(&den[ei[E + e] * 4 + h], ex);
}

// ============ K5: Z[dst,:] += sum_h alpha_h * Y[src,h,:] ============
__global__ __launch_bounds__(256) void scatter_z(
    const __hip_bfloat16* __restrict__ Y, const int* __restrict__ ei,
    const float* __restrict__ exb, const float* __restrict__ den,
    float* __restrict__ Z, int E)
{
    int e = blockIdx.x, t = threadIdx.x;
    int src = ei[e], dst = ei[E + e];
    float al[4];
    #pragma unroll
    for (int h = 0; h < 4; ++h)
        al[h] = exb[e * 4 + h] / (den[dst * 4 + h] + 1e-16f);
    int c = t * 2;
    float z0 = 0.f, z1 = 0.f;
    #pragma unroll
    for (int h = 0; h < 4; ++h) {
        uint32 q = *(const uint32*)((const unsigned short*)Y + ((size_t)src * 4 + h) * 512 + c);
        z0 += al[h] * bf_lo(q);
        z1 += al[h] * bf_hi(q);
    }
    atomicAdd(&Z[(size_t)dst * 512 + c], z0);
    atomicAdd(&Z[(size_t)dst * 512 + c + 1], z1);
}

// ============ K6: bias2 = b_d1 + conv_bias @ W_d1 ============
__global__ __launch_bounds__(256) void bias2_kernel(
    const float* __restrict__ bd1, const float* __restrict__ cb,
    const float* __restrict__ Wd1, float* __restrict__ bias2)
{
    int j = blockIdx.x * 256 + threadIdx.x;
    if (j >= 512) return;
    float acc = bd1[j];
    for (int k = 0; k < 2048; ++k) acc += cb[k] * Wd1[(size_t)k * 512 + j];
    bias2[j] = acc;
}

// ============ K7: out = sigmoid(relu(Z+bias2) @ W_d2 + b_d2) ============
__global__ __launch_bounds__(256) void decoder(
    const float* __restrict__ Z, const float* __restrict__ bias2,
    const float* __restrict__ Wd2, const float* __restrict__ bd2,
    float* __restrict__ out, int M)
{
    int node = (blockIdx.x * 256 + threadIdx.x) >> 6;
    int lane = threadIdx.x & 63;
    if (node >= M) return;
    const float* zr = Z + (size_t)node * 512;
    float p[6] = {0.f, 0.f, 0.f, 0.f, 0.f, 0.f};
    #pragma unroll
    for (int k = 0; k < 8; ++k) {
        int c = lane + k * 64;
        float a = fmaxf(zr[c] + bias2[c], 0.f);
        #pragma unroll
        for (int j = 0; j < 6; ++j) p[j] += a * Wd2[c * 6 + j];
    }
    #pragma unroll
    for (int off = 32; off; off >>= 1)
        #pragma unroll
        for (int j = 0; j < 6; ++j) p[j] += __shfl_down(p[j], off);
    if (lane == 0) {
        #pragma unroll
        for (int j = 0; j < 6; ++j)
            out[(size_t)node * 6 + j] = 1.f / (1.f + expf(-(p[j] + bd2[j])));
    }
}

extern "C" void kernel_launch(void* const* d_in, const int* in_sizes, int n_in,
                              void* d_out, int out_size, void* d_ws, size_t ws_size,
                              hipStream_t stream)
{
    const float* x         = (const float*)d_in[0];
    const float* edge_attr = (const float*)d_in[1];
    const int*   ei        = (const int*)d_in[2];
    const float* W_node = (const float*)d_in[3],  *b_node = (const float*)d_in[4];
    const float* W_edge = (const float*)d_in[5],  *b_edge = (const float*)d_in[6];
    const float* W_l    = (const float*)d_in[7],  *b_l    = (const float*)d_in[8];
    const float* W_r    = (const float*)d_in[9],  *b_r    = (const float*)d_in[10];
    const float* W_le   = (const float*)d_in[11];
    const float* att    = (const float*)d_in[12];
    const float* conv_bias = (const float*)d_in[13];
    const float* W_d1   = (const float*)d_in[14], *b_d1 = (const float*)d_in[15];
    const float* W_d2   = (const float*)d_in[16], *b_d2 = (const float*)d_in[17];
    float* out = (float*)d_out;

    const int N = in_sizes[0] / 7;   // 25000
    const int E = in_sizes[1] / 2;   // 50000

    // ---- workspace layout (~258 MB) ----
    char* ws = (char*)d_ws;
    const size_t sz_XL = (size_t)N * 2048 * 2;        // bf16 [N,2048]
    const size_t o_XL = 0;
    const size_t o_XR = o_XL + sz_XL;                 // XR; later reused as Y [N,4,512] bf16
    const size_t o_Z  = o_XR + sz_XL;
    const size_t sz_Z = (size_t)N * 512 * 4;          // fp32 [N,512]
    const size_t o_lg = o_Z + sz_Z;
    const size_t sz_lg = (size_t)E * 4 * 4;
    const size_t o_ex = o_lg + sz_lg;
    const size_t o_dn = o_ex + sz_lg;
    const size_t sz_dn = (size_t)N * 4 * 4;
    const size_t o_b2 = o_dn + sz_dn;
    const size_t need = o_b2 + 512 * 4;
    if (ws_size < need) return;  // diagnostic: clean fail (absmax~0.5) instead of fault

    __hip_bfloat16* XL = (__hip_bfloat16*)(ws + o_XL);
    __hip_bfloat16* XR = (__hip_bfloat16*)(ws + o_XR);
    __hip_bfloat16* Y  = (__hip_bfloat16*)(ws + o_XR);  // overlays XR (dead after logits)
    float* Z      = (float*)(ws + o_Z);
    float* logits = (float*)(ws + o_lg);
    float* exb    = (float*)(ws + o_ex);
    float* den    = (float*)(ws + o_dn);
    float* bias2  = (float*)(ws + o_b2);

    hipMemsetAsync(logits, 0, sz_lg, stream);
    hipMemsetAsync(den, 0, sz_dn, stream);
    hipMemsetAsync(Z, 0, sz_Z, stream);

    dim3 gN((N + TILE - 1) / TILE, 2048 / TILE);
    node_gemm<<<gN, 256, 0, stream>>>(x, W_node, b_node, W_l, b_l, XL, N);
    node_gemm<<<gN, 256, 0, stream>>>(x, W_node, b_node, W_r, b_r, XR, N);

    dim3 gE((E + TILE - 1) / TILE, 2048 / TILE);
    edge_gemm_logits<<<gE, 256, 0, stream>>>(edge_attr, W_edge, b_edge, W_le,
                                             XL, XR, ei, att, logits, E);

    softmax_den<<<(E * 4 + 255) / 256, 256, 0, stream>>>(logits, ei, exb, den, E);

    dim3 gY((N + TILE - 1) / TILE, 512 / TILE, 4);
    y_gemm<<<gY, 256, 0, stream>>>(XL, W_d1, Y, N);   // writes over XR region

    bias2_kernel<<<2, 256, 0, stream>>>(b_d1, conv_bias, W_d1, bias2);

    scatter_z<<<E, 256, 0, stream>>>(Y, ei, exb, den, Z, E);

    decoder<<<(N * 64 + 255) / 256, 256, 0, stream>>>(Z, bias2, W_d2, b_d2, out, N);
}

// Round 3
// 1241.878 us; speedup vs baseline: 3.1108x; 3.1108x over previous
//
#include <hip/hip_runtime.h>
#include <hip/hip_bf16.h>

typedef __attribute__((ext_vector_type(8))) short short8;   // 8 bf16 = 4 VGPRs
typedef __attribute__((ext_vector_type(4))) float f32x4;
typedef unsigned int uint32;

#define LDP 132   // padded rows per k-chunk panel (bank-friendly: 16g+4r spread)
#define FR(g,row) (((g)*LDP + (row)) * 8)

__device__ __forceinline__ float bf_lo(uint32 q) {
    union { uint32 u; float f; } v; v.u = q << 16; return v.f;
}
__device__ __forceinline__ float bf_hi(uint32 q) {
    union { uint32 u; float f; } v; v.u = q & 0xffff0000u; return v.f;
}
__device__ __forceinline__ void storev(float* p, float v) { *p = v; }
__device__ __forceinline__ void storev(__hip_bfloat16* p, float v) { *p = __float2bfloat16(v); }

// ============ transpose fp32 [K,N] -> bf16 [N,K] ============
__global__ __launch_bounds__(256) void transpose_bf16(
    const float* __restrict__ W, __hip_bfloat16* __restrict__ WT, int K, int N)
{
    __shared__ float tile[32][33];
    int k0 = blockIdx.x * 32, n0 = blockIdx.y * 32;
    int tx = threadIdx.x & 31, ty = threadIdx.x >> 5;   // 32 x 8
    #pragma unroll
    for (int i = 0; i < 32; i += 8)
        tile[ty + i][tx] = W[(size_t)(k0 + ty + i) * N + n0 + tx];
    __syncthreads();
    #pragma unroll
    for (int i = 0; i < 32; i += 8)
        WT[(size_t)(n0 + ty + i) * K + k0 + tx] = __float2bfloat16(tile[tx][ty + i]);
}

// ============ node encoder: h = relu(x@Wn+bn) bf16 [N,512] ============
__global__ __launch_bounds__(256) void encode_nodes(
    const float* __restrict__ x, const float* __restrict__ Wn,
    const float* __restrict__ bn, __hip_bfloat16* __restrict__ h, int Nn)
{
    int idx = blockIdx.x * 256 + threadIdx.x;
    if (idx >= Nn * 512) return;
    int n = idx >> 9, c = idx & 511;
    float acc = bn[c];
    #pragma unroll
    for (int f = 0; f < 7; ++f) acc += x[n * 7 + f] * Wn[f * 512 + c];
    h[idx] = __float2bfloat16(fmaxf(acc, 0.f));
}

// ============ generic bf16 MFMA GEMM: C = A @ BT^T (+bias) ============
// A [M,K] bf16 row-major (lda), BT [Ncols,K] bf16 row-major (ldb),
// C [M,Ncols] (ldc). Grid: (ceil(M/128), Ncols/128). Block 256 = 4 waves.
template <typename OutT, bool HAS_BIAS>
__global__ __launch_bounds__(256) void mfma_gemm(
    const __hip_bfloat16* __restrict__ A, int lda,
    const __hip_bfloat16* __restrict__ BT, int ldb,
    const float* __restrict__ bias,
    OutT* __restrict__ C, int ldc, int M, int K)
{
    __shared__ __hip_bfloat16 As[4 * LDP * 8];
    __shared__ __hip_bfloat16 Bs[4 * LDP * 8];
    const int t = threadIdx.x;
    const int lane = t & 63, w = t >> 6;
    const int wr = (w >> 1) * 64, wc = (w & 1) * 64;
    const int row0 = blockIdx.x * 128, col0 = blockIdx.y * 128;
    const int srow = t >> 2, sg = t & 3;
    const int lr = lane & 15, lg = lane >> 4;

    f32x4 acc[4][4];
    #pragma unroll
    for (int m = 0; m < 4; ++m)
        #pragma unroll
        for (int n = 0; n < 4; ++n) acc[m][n] = 0.f;

    for (int k0 = 0; k0 < K; k0 += 32) {
        uint4 av[2], bv[2];
        #pragma unroll
        for (int p = 0; p < 2; ++p) {
            int row = p * 64 + srow;
            int gr = row0 + row;
            av[p] = (gr < M) ? *(const uint4*)(A + (size_t)gr * lda + k0 + sg * 8)
                             : make_uint4(0, 0, 0, 0);
            bv[p] = *(const uint4*)(BT + (size_t)(col0 + row) * ldb + k0 + sg * 8);
        }
        __syncthreads();
        #pragma unroll
        for (int p = 0; p < 2; ++p) {
            int row = p * 64 + srow;
            *(uint4*)&As[FR(sg, row)] = av[p];
            *(uint4*)&Bs[FR(sg, row)] = bv[p];
        }
        __syncthreads();
        short8 af[4], bfr[4];
        #pragma unroll
        for (int m = 0; m < 4; ++m) af[m]  = *(const short8*)&As[FR(lg, wr + m * 16 + lr)];
        #pragma unroll
        for (int n = 0; n < 4; ++n) bfr[n] = *(const short8*)&Bs[FR(lg, wc + n * 16 + lr)];
        #pragma unroll
        for (int m = 0; m < 4; ++m)
            #pragma unroll
            for (int n = 0; n < 4; ++n)
                acc[m][n] = __builtin_amdgcn_mfma_f32_16x16x32_bf16(af[m], bfr[n], acc[m][n], 0, 0, 0);
    }

    #pragma unroll
    for (int m = 0; m < 4; ++m) {
        #pragma unroll
        for (int r = 0; r < 4; ++r) {
            int gr = row0 + wr + m * 16 + lg * 4 + r;
            if (gr >= M) continue;
            #pragma unroll
            for (int n = 0; n < 4; ++n) {
                int gc = col0 + wc + n * 16 + lr;
                float v = acc[m][n][r];
                if (HAS_BIAS) v += bias[gc];
                storev(&C[(size_t)gr * ldc + gc], v);
            }
        }
    }
}

// ============ edge MFMA GEMM (encoder fused in A-staging) + logits epilogue ===
// EE tile = relu(edge_attr@We+be) @ WleT^T ; logits[e,h] += sum att*leaky(EE+XL[src]+XR[dst])
__global__ __launch_bounds__(256) void edge_mfma_logits(
    const float* __restrict__ eat,   // [E,2]
    const float* __restrict__ We,    // [2,512]
    const float* __restrict__ be,    // [512]
    const __hip_bfloat16* __restrict__ WleT,  // [2048,512]
    const __hip_bfloat16* __restrict__ XL,
    const __hip_bfloat16* __restrict__ XR,
    const int* __restrict__ ei,      // [2,E]
    const float* __restrict__ att,   // [4,512]
    float* __restrict__ logits,      // [E,4] pre-zeroed
    int E)
{
    __shared__ __hip_bfloat16 As[4 * LDP * 8];
    __shared__ __hip_bfloat16 Bs[4 * LDP * 8];
    __shared__ float es0[128], es1[128];
    __shared__ int srcs[128], dsts[128];

    const int t = threadIdx.x;
    const int lane = t & 63, w = t >> 6;
    const int wr = (w >> 1) * 64, wc = (w & 1) * 64;
    const int row0 = blockIdx.x * 128, col0 = blockIdx.y * 128;
    const int srow = t >> 2, sg = t & 3;
    const int lr = lane & 15, lg = lane >> 4;

    if (t < 128) {
        int ge = row0 + t;
        bool ok = ge < E;
        es0[t] = ok ? eat[ge * 2] : 0.f;
        es1[t] = ok ? eat[ge * 2 + 1] : 0.f;
        srcs[t] = ok ? ei[ge] : 0;
        dsts[t] = ok ? ei[E + ge] : 0;
    }
    __syncthreads();

    f32x4 acc[4][4];
    #pragma unroll
    for (int m = 0; m < 4; ++m)
        #pragma unroll
        for (int n = 0; n < 4; ++n) acc[m][n] = 0.f;

    for (int k0 = 0; k0 < 512; k0 += 32) {
        // weight slices for this thread's 8 k-values
        float4 w0a = *(const float4*)(We + k0 + sg * 8);
        float4 w0b = *(const float4*)(We + k0 + sg * 8 + 4);
        float4 w1a = *(const float4*)(We + 512 + k0 + sg * 8);
        float4 w1b = *(const float4*)(We + 512 + k0 + sg * 8 + 4);
        float4 ba  = *(const float4*)(be + k0 + sg * 8);
        float4 bb  = *(const float4*)(be + k0 + sg * 8 + 4);
        float w0[8] = {w0a.x, w0a.y, w0a.z, w0a.w, w0b.x, w0b.y, w0b.z, w0b.w};
        float w1[8] = {w1a.x, w1a.y, w1a.z, w1a.w, w1b.x, w1b.y, w1b.z, w1b.w};
        float bv8[8] = {ba.x, ba.y, ba.z, ba.w, bb.x, bb.y, bb.z, bb.w};

        uint4 av[2], bvv[2];
        #pragma unroll
        for (int p = 0; p < 2; ++p) {
            int row = p * 64 + srow;
            float e0 = es0[row], e1 = es1[row];
            alignas(16) __hip_bfloat16 tmp[8];
            #pragma unroll
            for (int j = 0; j < 8; ++j) {
                float v = fmaf(e0, w0[j], fmaf(e1, w1[j], bv8[j]));
                tmp[j] = __float2bfloat16(fmaxf(v, 0.f));
            }
            av[p] = *(const uint4*)tmp;
            bvv[p] = *(const uint4*)(WleT + (size_t)(col0 + row) * 512 + k0 + sg * 8);
        }
        __syncthreads();
        #pragma unroll
        for (int p = 0; p < 2; ++p) {
            int row = p * 64 + srow;
            *(uint4*)&As[FR(sg, row)] = av[p];
            *(uint4*)&Bs[FR(sg, row)] = bvv[p];
        }
        __syncthreads();
        short8 af[4], bfr[4];
        #pragma unroll
        for (int m = 0; m < 4; ++m) af[m]  = *(const short8*)&As[FR(lg, wr + m * 16 + lr)];
        #pragma unroll
        for (int n = 0; n < 4; ++n) bfr[n] = *(const short8*)&Bs[FR(lg, wc + n * 16 + lr)];
        #pragma unroll
        for (int m = 0; m < 4; ++m)
            #pragma unroll
            for (int n = 0; n < 4; ++n)
                acc[m][n] = __builtin_amdgcn_mfma_f32_16x16x32_bf16(af[m], bfr[n], acc[m][n], 0, 0, 0);
    }

    // logits epilogue: C layout col=lane&15, row=(lane>>4)*4+reg
    int h = col0 >> 9;
    float attv[4];
    #pragma unroll
    for (int n = 0; n < 4; ++n) {
        int gc = col0 + wc + n * 16 + lr;
        attv[n] = att[h * 512 + (gc & 511)];
    }
    #pragma unroll
    for (int m = 0; m < 4; ++m) {
        #pragma unroll
        for (int r = 0; r < 4; ++r) {
            int row = wr + m * 16 + lg * 4 + r;
            int ge = row0 + row;
            const __hip_bfloat16* xlp = XL + (size_t)srcs[row] * 2048;
            const __hip_bfloat16* xrp = XR + (size_t)dsts[row] * 2048;
            float part = 0.f;
            #pragma unroll
            for (int n = 0; n < 4; ++n) {
                int gc = col0 + wc + n * 16 + lr;
                float mval = acc[m][n][r] + __bfloat162float(xlp[gc]) + __bfloat162float(xrp[gc]);
                part += attv[n] * ((mval > 0.f) ? mval : 0.2f * mval);
            }
            part += __shfl_xor(part, 1);
            part += __shfl_xor(part, 2);
            part += __shfl_xor(part, 4);
            part += __shfl_xor(part, 8);
            if (lr == 0 && ge < E) atomicAdd(&logits[ge * 4 + h], part);
        }
    }
}

// ============ exp + denominator scatter ============
__global__ __launch_bounds__(256) void softmax_den(
    const float* __restrict__ logits, const int* __restrict__ ei,
    float* __restrict__ exb, float* __restrict__ den, int E)
{
    int idx = blockIdx.x * 256 + threadIdx.x;
    if (idx >= E * 4) return;
    int e = idx >> 2, h = idx & 3;
    float ex = expf(logits[idx]);   // softmax shift-invariant; logits O(0.1)
    exb[idx] = ex;
    atomicAdd(&den[ei[E + e] * 4 + h], ex);
}

// ============ Z[dst,:] += sum_h alpha_h * Y[src,h,:] ============
__global__ __launch_bounds__(256) void scatter_z(
    const __hip_bfloat16* __restrict__ Y, const int* __restrict__ ei,
    const float* __restrict__ exb, const float* __restrict__ den,
    float* __restrict__ Z, int E)
{
    int e = blockIdx.x, t = threadIdx.x;
    int src = ei[e], dst = ei[E + e];
    float al[4];
    #pragma unroll
    for (int h = 0; h < 4; ++h)
        al[h] = exb[e * 4 + h] / (den[dst * 4 + h] + 1e-16f);
    int c = t * 2;
    float z0 = 0.f, z1 = 0.f;
    #pragma unroll
    for (int h = 0; h < 4; ++h) {
        uint32 q = *(const uint32*)((const unsigned short*)Y + ((size_t)src * 4 + h) * 512 + c);
        z0 += al[h] * bf_lo(q);
        z1 += al[h] * bf_hi(q);
    }
    atomicAdd(&Z[(size_t)dst * 512 + c], z0);
    atomicAdd(&Z[(size_t)dst * 512 + c + 1], z1);
}

// ============ bias2 = b_d1 + conv_bias @ W_d1 ============
__global__ __launch_bounds__(256) void bias2_kernel(
    const float* __restrict__ bd1, const float* __restrict__ cb,
    const float* __restrict__ Wd1, float* __restrict__ bias2)
{
    int j = blockIdx.x * 256 + threadIdx.x;
    if (j >= 512) return;
    float acc = bd1[j];
    for (int k = 0; k < 2048; ++k) acc += cb[k] * Wd1[(size_t)k * 512 + j];
    bias2[j] = acc;
}

// ============ out = sigmoid(relu(Z+bias2) @ W_d2 + b_d2) ============
__global__ __launch_bounds__(256) void decoder(
    const float* __restrict__ Z, const float* __restrict__ bias2,
    const float* __restrict__ Wd2, const float* __restrict__ bd2,
    float* __restrict__ out, int M)
{
    int node = (blockIdx.x * 256 + threadIdx.x) >> 6;
    int lane = threadIdx.x & 63;
    if (node >= M) return;
    const float* zr = Z + (size_t)node * 512;
    float p[6] = {0.f, 0.f, 0.f, 0.f, 0.f, 0.f};
    #pragma unroll
    for (int k = 0; k < 8; ++k) {
        int c = lane + k * 64;
        float a = fmaxf(zr[c] + bias2[c], 0.f);
        #pragma unroll
        for (int j = 0; j < 6; ++j) p[j] += a * Wd2[c * 6 + j];
    }
    #pragma unroll
    for (int off = 32; off; off >>= 1)
        #pragma unroll
        for (int j = 0; j < 6; ++j) p[j] += __shfl_down(p[j], off);
    if (lane == 0) {
        #pragma unroll
        for (int j = 0; j < 6; ++j)
            out[(size_t)node * 6 + j] = 1.f / (1.f + expf(-(p[j] + bd2[j])));
    }
}

extern "C" void kernel_launch(void* const* d_in, const int* in_sizes, int n_in,
                              void* d_out, int out_size, void* d_ws, size_t ws_size,
                              hipStream_t stream)
{
    const float* x         = (const float*)d_in[0];
    const float* edge_attr = (const float*)d_in[1];
    const int*   ei        = (const int*)d_in[2];
    const float* W_node = (const float*)d_in[3],  *b_node = (const float*)d_in[4];
    const float* W_edge = (const float*)d_in[5],  *b_edge = (const float*)d_in[6];
    const float* W_l    = (const float*)d_in[7],  *b_l    = (const float*)d_in[8];
    const float* W_r    = (const float*)d_in[9],  *b_r    = (const float*)d_in[10];
    const float* W_le   = (const float*)d_in[11];
    const float* att    = (const float*)d_in[12];
    const float* conv_bias = (const float*)d_in[13];
    const float* W_d1   = (const float*)d_in[14], *b_d1 = (const float*)d_in[15];
    const float* W_d2   = (const float*)d_in[16], *b_d2 = (const float*)d_in[17];
    float* out = (float*)d_out;

    const int N = in_sizes[0] / 7;   // 25000
    const int E = in_sizes[1] / 2;   // 50000

    // ---- workspace layout (~266 MB) ----
    char* ws = (char*)d_ws;
    const size_t szZ   = (size_t)N * 512 * 4;     // region0: h bf16 (25.6MB) then Z fp32 (51.2MB)
    const size_t szX   = (size_t)N * 2048 * 2;    // bf16 [N,2048]
    const size_t szW   = (size_t)2048 * 512 * 2;  // bf16 weight panel
    const size_t o_XL  = szZ;
    const size_t o_XR  = o_XL + szX;
    const size_t o_WlT = o_XR + szX;
    const size_t o_WrT = o_WlT + szW;
    const size_t o_WleT= o_WrT + szW;
    const size_t o_Wd1T= o_WleT + szW;
    const size_t o_lg  = o_Wd1T + szW;
    const size_t szlg  = (size_t)E * 4 * 4;
    const size_t o_ex  = o_lg + szlg;
    const size_t o_dn  = o_ex + szlg;
    const size_t o_b2  = o_dn + (size_t)N * 4 * 4;
    const size_t need  = o_b2 + 512 * 4;
    if (ws_size < need) return;   // clean diagnostic failure if ws too small

    __hip_bfloat16* h   = (__hip_bfloat16*)(ws);          // region0 as bf16 h
    float*          Z   = (float*)(ws);                   // region0 as fp32 Z (after h dead)
    __hip_bfloat16* XL  = (__hip_bfloat16*)(ws + o_XL);
    __hip_bfloat16* XR  = (__hip_bfloat16*)(ws + o_XR);
    __hip_bfloat16* Y   = XR;                             // overlays XR after logits
    __hip_bfloat16* WlT = (__hip_bfloat16*)(ws + o_WlT);
    __hip_bfloat16* WrT = (__hip_bfloat16*)(ws + o_WrT);
    __hip_bfloat16* WleT= (__hip_bfloat16*)(ws + o_WleT);
    __hip_bfloat16* Wd1T= (__hip_bfloat16*)(ws + o_Wd1T);
    float* logits = (float*)(ws + o_lg);
    float* exb    = (float*)(ws + o_ex);
    float* den    = (float*)(ws + o_dn);
    float* bias2  = (float*)(ws + o_b2);

    hipMemsetAsync(logits, 0, szlg, stream);
    hipMemsetAsync(den, 0, (size_t)N * 4 * 4, stream);

    // weight prep: [K,N] fp32 -> [N,K] bf16
    dim3 gT(512 / 32, 2048 / 32);
    transpose_bf16<<<gT, 256, 0, stream>>>(W_l,  WlT, 512, 2048);
    transpose_bf16<<<gT, 256, 0, stream>>>(W_r,  WrT, 512, 2048);
    transpose_bf16<<<gT, 256, 0, stream>>>(W_le, WleT, 512, 2048);
    dim3 gT2(2048 / 32, 512 / 32);
    transpose_bf16<<<gT2, 256, 0, stream>>>(W_d1, Wd1T, 2048, 512);
    bias2_kernel<<<2, 256, 0, stream>>>(b_d1, conv_bias, W_d1, bias2);

    encode_nodes<<<(N * 512 + 255) / 256, 256, 0, stream>>>(x, W_node, b_node, h, N);

    const int MB = (N + 127) / 128;
    dim3 gXL(MB, 2048 / 128);
    mfma_gemm<__hip_bfloat16, true><<<gXL, 256, 0, stream>>>(h, 512, WlT, 512, b_l, XL, 2048, N, 512);
    mfma_gemm<__hip_bfloat16, true><<<gXL, 256, 0, stream>>>(h, 512, WrT, 512, b_r, XR, 2048, N, 512);

    dim3 gE((E + 127) / 128, 2048 / 128);
    edge_mfma_logits<<<gE, 256, 0, stream>>>(edge_attr, W_edge, b_edge, WleT,
                                             XL, XR, ei, att, logits, E);

    softmax_den<<<(E * 4 + 255) / 256, 256, 0, stream>>>(logits, ei, exb, den, E);

    // Y[n, h*512+c] = XL[n, h*512: ] @ W_d1[h*512: , :]   (per-head block-diag)
    dim3 gY(MB, 512 / 128);
    for (int hh = 0; hh < 4; ++hh)
        mfma_gemm<__hip_bfloat16, false><<<gY, 256, 0, stream>>>(
            XL + hh * 512, 2048, Wd1T + hh * 512, 2048, nullptr,
            Y + hh * 512, 2048, N, 512);

    hipMemsetAsync(Z, 0, szZ, stream);
    scatter_z<<<E, 256, 0, stream>>>(Y, ei, exb, den, Z, E);

    decoder<<<(N * 64 + 255) / 256, 256, 0, stream>>>(Z, bias2, W_d2, b_d2, out, N);
}

// Round 4
// 910.355 us; speedup vs baseline: 4.2437x; 1.3642x over previous
//
#include <hip/hip_runtime.h>
#include <hip/hip_bf16.h>

typedef __attribute__((ext_vector_type(8))) short short8;
typedef __attribute__((ext_vector_type(4))) float f32x4;
typedef unsigned int uint32;

// async global->LDS, 16B per lane; LDS dest = uniform base + lane*16
#define GLD16(g, l) __builtin_amdgcn_global_load_lds( \
    (const __attribute__((address_space(1))) unsigned int*)(g), \
    (__attribute__((address_space(3))) unsigned int*)(l), 16, 0, 0)

__device__ __forceinline__ float bfu(unsigned short u) {
    union { uint32 v; float f; } x; x.v = ((uint32)u) << 16; return x.f;
}
__device__ __forceinline__ void storev(float* p, float v) { *p = v; }
__device__ __forceinline__ void storev(__hip_bfloat16* p, float v) { *p = __float2bfloat16(v); }

// ============ transpose fp32 [K,N] -> bf16 [N,K] ============
__global__ __launch_bounds__(256) void transpose_bf16(
    const float* __restrict__ W, __hip_bfloat16* __restrict__ WT, int K, int N)
{
    __shared__ float tile[32][33];
    int k0 = blockIdx.x * 32, n0 = blockIdx.y * 32;
    int tx = threadIdx.x & 31, ty = threadIdx.x >> 5;   // 32 x 8
    #pragma unroll
    for (int i = 0; i < 32; i += 8)
        tile[ty + i][tx] = W[(size_t)(k0 + ty + i) * N + n0 + tx];
    __syncthreads();
    #pragma unroll
    for (int i = 0; i < 32; i += 8)
        WT[(size_t)(n0 + ty + i) * K + k0 + tx] = __float2bfloat16(tile[tx][ty + i]);
}

// ============ encoders ============
__global__ __launch_bounds__(256) void encode_nodes(
    const float* __restrict__ x, const float* __restrict__ Wn,
    const float* __restrict__ bn, __hip_bfloat16* __restrict__ h, int Nn)
{
    int idx = blockIdx.x * 256 + threadIdx.x;
    if (idx >= Nn * 512) return;
    int n = idx >> 9, c = idx & 511;
    float acc = bn[c];
    #pragma unroll
    for (int f = 0; f < 7; ++f) acc += x[n * 7 + f] * Wn[f * 512 + c];
    h[idx] = __float2bfloat16(fmaxf(acc, 0.f));
}

__global__ __launch_bounds__(256) void encode_edges(
    const float* __restrict__ eat, const float* __restrict__ We,
    const float* __restrict__ be, __hip_bfloat16* __restrict__ ea, int E)
{
    int idx = blockIdx.x * 256 + threadIdx.x;
    if (idx >= E * 512) return;
    int e = idx >> 9, c = idx & 511;
    float v = fmaf(eat[e * 2], We[c], fmaf(eat[e * 2 + 1], We[512 + c], be[c]));
    ea[idx] = __float2bfloat16(fmaxf(v, 0.f));
}

// ============ bf16 MFMA GEMM, m97-style global_load_lds staging ============
// A [Mpad,K] bf16 (lda), BT [Ncols,K] bf16 (ldb). C=[M,Ncols] (ldc).
// LDS tile [128 rows][32 k] bf16, k-chunk XOR-swizzled: stored chunkpos p holds
// global chunk p ^ ((row>>1)&3). A must be padded to grid rows (reads unguarded).
template <typename OutT, bool HAS_BIAS>
__global__ __launch_bounds__(256) void mfma_gemm(
    const __hip_bfloat16* __restrict__ A, int lda, long az,
    const __hip_bfloat16* __restrict__ BT, int ldb, long bz,
    const float* __restrict__ bias,
    OutT* __restrict__ C, int ldc, long cz, int M, int K)
{
    __shared__ uint4 As4[512];   // 8 KB
    __shared__ uint4 Bs4[512];
    A  += (long)blockIdx.z * az;
    BT += (long)blockIdx.z * bz;
    C  += (long)blockIdx.z * cz;
    const int t = threadIdx.x, lane = t & 63, w = t >> 6;
    const int wr = (w >> 1) * 64, wc = (w & 1) * 64;
    const int row0 = blockIdx.x * 128, col0 = blockIdx.y * 128;
    const int lr = lane & 15, lg = lane >> 4;
    const int r0 = w * 16 + (lane >> 2);                     // staging row, seg w
    const int ksw = ((lane & 3) ^ ((lane >> 3) & 3)) * 8;    // swizzled k-chunk (elems)
    const int rsw = (lg ^ ((lr >> 1) & 3)) << 4;             // read-side swizzle (bytes)

    const __hip_bfloat16* Ap0 = A + (size_t)(row0 + r0) * lda + ksw;
    const __hip_bfloat16* Ap1 = A + (size_t)(row0 + r0 + 64) * lda + ksw;
    const __hip_bfloat16* Bp0 = BT + (size_t)(col0 + r0) * ldb + ksw;
    const __hip_bfloat16* Bp1 = BT + (size_t)(col0 + r0 + 64) * ldb + ksw;
    char* AsB = (char*)As4; char* BsB = (char*)Bs4;
    uint4* la0 = As4 + w * 64;       uint4* la1 = As4 + (w + 4) * 64;
    uint4* lb0 = Bs4 + w * 64;       uint4* lb1 = Bs4 + (w + 4) * 64;

    f32x4 acc[4][4];
    #pragma unroll
    for (int m = 0; m < 4; ++m)
        #pragma unroll
        for (int n = 0; n < 4; ++n) acc[m][n] = 0.f;

    for (int k0 = 0; k0 < K; k0 += 32) {
        GLD16(Ap0 + k0, la0);
        GLD16(Ap1 + k0, la1);
        GLD16(Bp0 + k0, lb0);
        GLD16(Bp1 + k0, lb1);
        __syncthreads();
        short8 af[4], bfrag[4];
        #pragma unroll
        for (int m = 0; m < 4; ++m)
            af[m] = *(const short8*)(AsB + (wr + m * 16 + lr) * 64 + rsw);
        #pragma unroll
        for (int n = 0; n < 4; ++n)
            bfrag[n] = *(const short8*)(BsB + (wc + n * 16 + lr) * 64 + rsw);
        #pragma unroll
        for (int m = 0; m < 4; ++m)
            #pragma unroll
            for (int n = 0; n < 4; ++n)
                acc[m][n] = __builtin_amdgcn_mfma_f32_16x16x32_bf16(af[m], bfrag[n], acc[m][n], 0, 0, 0);
        __syncthreads();
    }

    #pragma unroll
    for (int m = 0; m < 4; ++m) {
        #pragma unroll
        for (int r = 0; r < 4; ++r) {
            int gr = row0 + wr + m * 16 + lg * 4 + r;
            if (gr >= M) continue;
            #pragma unroll
            for (int n = 0; n < 4; ++n) {
                int gc = col0 + wc + n * 16 + lr;
                float v = acc[m][n][r];
                if (HAS_BIAS) v += bias[gc];
                storev(&C[(size_t)gr * ldc + gc], v);
            }
        }
    }
}

// ============ edge GEMM (EE = ea @ WleT^T) + fused logits epilogue ============
__global__ __launch_bounds__(256) void edge_mfma_logits(
    const __hip_bfloat16* __restrict__ ea,    // [EP,512]
    const __hip_bfloat16* __restrict__ WleT,  // [2048,512]
    const __hip_bfloat16* __restrict__ XL,
    const __hip_bfloat16* __restrict__ XR,
    const int* __restrict__ ei,
    const float* __restrict__ att,
    float* __restrict__ logits,               // [E,4] pre-zeroed
    int E)
{
    __shared__ uint4 As4[512];
    __shared__ uint4 Bs4[512];
    __shared__ int srcs[128], dsts[128];
    const int t = threadIdx.x, lane = t & 63, w = t >> 6;
    const int wr = (w >> 1) * 64, wc = (w & 1) * 64;
    const int row0 = blockIdx.x * 128, col0 = blockIdx.y * 128;
    const int lr = lane & 15, lg = lane >> 4;
    const int r0 = w * 16 + (lane >> 2);
    const int ksw = ((lane & 3) ^ ((lane >> 3) & 3)) * 8;
    const int rsw = (lg ^ ((lr >> 1) & 3)) << 4;

    if (t < 128) {
        int ge = row0 + t;
        bool ok = ge < E;
        srcs[t] = ok ? ei[ge] : 0;
        dsts[t] = ok ? ei[E + ge] : 0;
    }
    char* AsB = (char*)As4; char* BsB = (char*)Bs4;
    uint4* la0 = As4 + w * 64;       uint4* la1 = As4 + (w + 4) * 64;
    uint4* lb0 = Bs4 + w * 64;       uint4* lb1 = Bs4 + (w + 4) * 64;
    const __hip_bfloat16* Ap0 = ea + (size_t)(row0 + r0) * 512 + ksw;
    const __hip_bfloat16* Ap1 = ea + (size_t)(row0 + r0 + 64) * 512 + ksw;
    const __hip_bfloat16* Bp0 = WleT + (size_t)(col0 + r0) * 512 + ksw;
    const __hip_bfloat16* Bp1 = WleT + (size_t)(col0 + r0 + 64) * 512 + ksw;
    __syncthreads();

    f32x4 acc[4][4];
    #pragma unroll
    for (int m = 0; m < 4; ++m)
        #pragma unroll
        for (int n = 0; n < 4; ++n) acc[m][n] = 0.f;

    for (int k0 = 0; k0 < 512; k0 += 32) {
        GLD16(Ap0 + k0, la0);
        GLD16(Ap1 + k0, la1);
        GLD16(Bp0 + k0, lb0);
        GLD16(Bp1 + k0, lb1);
        __syncthreads();
        short8 af[4], bfrag[4];
        #pragma unroll
        for (int m = 0; m < 4; ++m)
            af[m] = *(const short8*)(AsB + (wr + m * 16 + lr) * 64 + rsw);
        #pragma unroll
        for (int n = 0; n < 4; ++n)
            bfrag[n] = *(const short8*)(BsB + (wc + n * 16 + lr) * 64 + rsw);
        #pragma unroll
        for (int m = 0; m < 4; ++m)
            #pragma unroll
            for (int n = 0; n < 4; ++n)
                acc[m][n] = __builtin_amdgcn_mfma_f32_16x16x32_bf16(af[m], bfrag[n], acc[m][n], 0, 0, 0);
        __syncthreads();
    }

    // ---- logits epilogue: stage XL/XR 32-col strips into reused As/Bs ----
    const int hh = col0 >> 9;
    float attv[4];
    #pragma unroll
    for (int n = 0; n < 4; ++n)
        attv[n] = att[hh * 512 + ((col0 + wc + n * 16 + lr) & 511)];
    float part[4][4];
    #pragma unroll
    for (int m = 0; m < 4; ++m)
        #pragma unroll
        for (int r = 0; r < 4; ++r) part[m][r] = 0.f;

    const int prt = (lane & 3) * 8;   // 8-elem sub-chunk within 32-col strip
    #pragma unroll
    for (int ch = 0; ch < 4; ++ch) {
        __syncthreads();   // previous strip/tile reads done
        int cc = col0 + ch * 32;
        GLD16(XL + (size_t)srcs[r0] * 2048 + cc + prt, la0);
        GLD16(XL + (size_t)srcs[r0 + 64] * 2048 + cc + prt, la1);
        GLD16(XR + (size_t)dsts[r0] * 2048 + cc + prt, lb0);
        GLD16(XR + (size_t)dsts[r0 + 64] * 2048 + cc + prt, lb1);
        __syncthreads();
        #pragma unroll
        for (int n = 0; n < 4; ++n) {
            if (((wc + n * 16) >> 5) != ch) continue;
            int colin = ((n & 1) << 4) + lr;
            #pragma unroll
            for (int m = 0; m < 4; ++m) {
                #pragma unroll
                for (int r = 0; r < 4; ++r) {
                    int row = wr + m * 16 + lg * 4 + r;
                    float xl = bfu(*(const unsigned short*)(AsB + row * 64 + colin * 2));
                    float xr = bfu(*(const unsigned short*)(BsB + row * 64 + colin * 2));
                    float mv = acc[m][n][r] + xl + xr;
                    part[m][r] += attv[n] * ((mv > 0.f) ? mv : 0.2f * mv);
                }
            }
        }
    }
    #pragma unroll
    for (int m = 0; m < 4; ++m) {
        #pragma unroll
        for (int r = 0; r < 4; ++r) {
            float p = part[m][r];
            p += __shfl_xor(p, 1); p += __shfl_xor(p, 2);
            p += __shfl_xor(p, 4); p += __shfl_xor(p, 8);
            int ge = row0 + wr + m * 16 + lg * 4 + r;
            if (lr == 0 && ge < E) atomicAdd(&logits[ge * 4 + hh], p);
        }
    }
}

// ============ exp + denominator scatter ============
__global__ __launch_bounds__(256) void softmax_den(
    const float* __restrict__ logits, const int* __restrict__ ei,
    float* __restrict__ exb, float* __restrict__ den, int E)
{
    int idx = blockIdx.x * 256 + threadIdx.x;
    if (idx >= E * 4) return;
    int e = idx >> 2, h = idx & 3;
    float ex = expf(logits[idx]);   // softmax shift-invariant; logits O(0.1)
    exb[idx] = ex;
    atomicAdd(&den[ei[E + e] * 4 + h], ex);
}

// ============ Z[dst,:] += sum_h alpha_h * Y[src,h,:] ============
__global__ __launch_bounds__(256) void scatter_z(
    const __hip_bfloat16* __restrict__ Y, const int* __restrict__ ei,
    const float* __restrict__ exb, const float* __restrict__ den,
    float* __restrict__ Z, int E)
{
    int e = blockIdx.x, t = threadIdx.x;
    int src = ei[e], dst = ei[E + e];
    float al[4];
    #pragma unroll
    for (int h = 0; h < 4; ++h)
        al[h] = exb[e * 4 + h] / (den[dst * 4 + h] + 1e-16f);
    int c = t * 2;
    float z0 = 0.f, z1 = 0.f;
    #pragma unroll
    for (int h = 0; h < 4; ++h) {
        uint32 q = *(const uint32*)((const unsigned short*)Y + ((size_t)src * 4 + h) * 512 + c);
        z0 += al[h] * bfu((unsigned short)(q & 0xffff));
        z1 += al[h] * bfu((unsigned short)(q >> 16));
    }
    atomicAdd(&Z[(size_t)dst * 512 + c], z0);
    atomicAdd(&Z[(size_t)dst * 512 + c + 1], z1);
}

// ============ bias2 = b_d1 + conv_bias @ W_d1 ============
__global__ __launch_bounds__(256) void bias2_kernel(
    const float* __restrict__ bd1, const float* __restrict__ cb,
    const float* __restrict__ Wd1, float* __restrict__ bias2)
{
    int j = blockIdx.x * 256 + threadIdx.x;
    if (j >= 512) return;
    float acc = bd1[j];
    for (int k = 0; k < 2048; ++k) acc += cb[k] * Wd1[(size_t)k * 512 + j];
    bias2[j] = acc;
}

// ============ out = sigmoid(relu(Z+bias2) @ W_d2 + b_d2) ============
__global__ __launch_bounds__(256) void decoder(
    const float* __restrict__ Z, const float* __restrict__ bias2,
    const float* __restrict__ Wd2, const float* __restrict__ bd2,
    float* __restrict__ out, int M)
{
    int node = (blockIdx.x * 256 + threadIdx.x) >> 6;
    int lane = threadIdx.x & 63;
    if (node >= M) return;
    const float* zr = Z + (size_t)node * 512;
    float p[6] = {0.f, 0.f, 0.f, 0.f, 0.f, 0.f};
    #pragma unroll
    for (int k = 0; k < 8; ++k) {
        int c = lane + k * 64;
        float a = fmaxf(zr[c] + bias2[c], 0.f);
        #pragma unroll
        for (int j = 0; j < 6; ++j) p[j] += a * Wd2[c * 6 + j];
    }
    #pragma unroll
    for (int off = 32; off; off >>= 1)
        #pragma unroll
        for (int j = 0; j < 6; ++j) p[j] += __shfl_down(p[j], off);
    if (lane == 0) {
        #pragma unroll
        for (int j = 0; j < 6; ++j)
            out[(size_t)node * 6 + j] = 1.f / (1.f + expf(-(p[j] + bd2[j])));
    }
}

extern "C" void kernel_launch(void* const* d_in, const int* in_sizes, int n_in,
                              void* d_out, int out_size, void* d_ws, size_t ws_size,
                              hipStream_t stream)
{
    const float* x         = (const float*)d_in[0];
    const float* edge_attr = (const float*)d_in[1];
    const int*   ei        = (const int*)d_in[2];
    const float* W_node = (const float*)d_in[3],  *b_node = (const float*)d_in[4];
    const float* W_edge = (const float*)d_in[5],  *b_edge = (const float*)d_in[6];
    const float* W_l    = (const float*)d_in[7],  *b_l    = (const float*)d_in[8];
    const float* W_r    = (const float*)d_in[9],  *b_r    = (const float*)d_in[10];
    const float* W_le   = (const float*)d_in[11];
    const float* att    = (const float*)d_in[12];
    const float* conv_bias = (const float*)d_in[13];
    const float* W_d1   = (const float*)d_in[14], *b_d1 = (const float*)d_in[15];
    const float* W_d2   = (const float*)d_in[16], *b_d2 = (const float*)d_in[17];
    float* out = (float*)d_out;

    const int N = in_sizes[0] / 7;   // 25000
    const int E = in_sizes[1] / 2;   // 50000
    const int MP = (N + 127) & ~127; // padded rows (unguarded async A-reads)
    const int EP = (E + 127) & ~127;

    // ---- workspace layout (~267 MB) ----
    // region0 (51.25 MB) hosts, sequentially: h bf16[MP,512] -> ea bf16[EP,512] -> Z f32[N,512]
    char* ws = (char*)d_ws;
    const size_t szR0 = (size_t)EP * 512 * 2;     // >= max(h, ea, Z)
    const size_t szX  = (size_t)MP * 2048 * 2;
    const size_t szW  = (size_t)2048 * 512 * 2;
    const size_t o_XL = szR0;
    const size_t o_XR = o_XL + szX;
    const size_t o_W  = o_XR + szX;
    const size_t o_lg = o_W + 4 * szW;
    const size_t szlg = (size_t)E * 4 * 4;
    const size_t o_ex = o_lg + szlg;
    const size_t o_dn = o_ex + szlg;
    const size_t o_b2 = o_dn + (size_t)N * 4 * 4;
    const size_t need = o_b2 + 512 * 4;
    if (ws_size < need) return;   // clean diagnostic failure if ws too small

    __hip_bfloat16* h   = (__hip_bfloat16*)ws;
    __hip_bfloat16* ea  = (__hip_bfloat16*)ws;
    float*          Z   = (float*)ws;
    __hip_bfloat16* XL  = (__hip_bfloat16*)(ws + o_XL);
    __hip_bfloat16* XR  = (__hip_bfloat16*)(ws + o_XR);
    __hip_bfloat16* Y   = XR;                       // overlays XR after logits
    __hip_bfloat16* WlT = (__hip_bfloat16*)(ws + o_W);
    __hip_bfloat16* WrT = WlT + szW / 2;
    __hip_bfloat16* WleT= WrT + szW / 2;
    __hip_bfloat16* Wd1T= WleT + szW / 2;
    float* logits = (float*)(ws + o_lg);
    float* exb    = (float*)(ws + o_ex);
    float* den    = (float*)(ws + o_dn);
    float* bias2  = (float*)(ws + o_b2);

    hipMemsetAsync(logits, 0, szlg, stream);
    hipMemsetAsync(den, 0, (size_t)N * 4 * 4, stream);

    // weight prep: [K,N] fp32 -> [N,K] bf16
    dim3 gT(512 / 32, 2048 / 32);
    transpose_bf16<<<gT, 256, 0, stream>>>(W_l,  WlT, 512, 2048);
    transpose_bf16<<<gT, 256, 0, stream>>>(W_r,  WrT, 512, 2048);
    transpose_bf16<<<gT, 256, 0, stream>>>(W_le, WleT, 512, 2048);
    dim3 gT2(2048 / 32, 512 / 32);
    transpose_bf16<<<gT2, 256, 0, stream>>>(W_d1, Wd1T, 2048, 512);
    bias2_kernel<<<2, 256, 0, stream>>>(b_d1, conv_bias, W_d1, bias2);

    encode_nodes<<<(N * 512 + 255) / 256, 256, 0, stream>>>(x, W_node, b_node, h, N);

    const int MB = MP / 128;
    dim3 gNode(MB, 2048 / 128);
    mfma_gemm<__hip_bfloat16, true><<<gNode, 256, 0, stream>>>(
        h, 512, 0, WlT, 512, 0, b_l, XL, 2048, 0, N, 512);
    mfma_gemm<__hip_bfloat16, true><<<gNode, 256, 0, stream>>>(
        h, 512, 0, WrT, 512, 0, b_r, XR, 2048, 0, N, 512);

    // h dead -> region0 becomes ea
    encode_edges<<<(E * 512 + 255) / 256, 256, 0, stream>>>(edge_attr, W_edge, b_edge, ea, E);

    dim3 gE(EP / 128, 2048 / 128);
    edge_mfma_logits<<<gE, 256, 0, stream>>>(ea, WleT, XL, XR, ei, att, logits, E);

    softmax_den<<<(E * 4 + 255) / 256, 256, 0, stream>>>(logits, ei, exb, den, E);

    // Y[n, hh*512+c] = XL[n, hh*512:] @ W_d1[hh*512:, :]  (block-diag, one launch, grid.z=4)
    dim3 gY(MB, 512 / 128, 4);
    mfma_gemm<__hip_bfloat16, false><<<gY, 256, 0, stream>>>(
        XL, 2048, 512, Wd1T, 2048, 512, nullptr, Y, 2048, 512, N, 512);

    // ea dead -> region0 becomes Z
    hipMemsetAsync(Z, 0, (size_t)N * 512 * 4, stream);
    scatter_z<<<E, 256, 0, stream>>>(Y, ei, exb, den, Z, E);

    decoder<<<(N * 64 + 255) / 256, 256, 0, stream>>>(Z, bias2, W_d2, b_d2, out, N);
}